// Round 8
// baseline (34539.777 us; speedup 1.0000x reference)
//
#include <hip/hip_runtime.h>
#include <math.h>

#define KP 8192
#define TSTEPS 4096
#define BLOCK 1024
#define PT 8                 // particles per thread
#define NWAVES 16
#define NBUCK 8192
#define NBF 8192.0f
#define INV_NB (1.0f / 8192.0f)
#define RS_LU 8208           // u16 row stride for L_u (16416B, 16B aligned)

// ---------------- DPP wave-scan helpers (pure VALU, no LDS pipe) ----------------
template <int CTRL, int RM>
__device__ __forceinline__ float dpp_add_f(float x) {
  int s = __builtin_amdgcn_update_dpp(0, __float_as_int(x), CTRL, RM, 0xF, false);
  return x + __int_as_float(s);
}
template <int CTRL, int RM>
__device__ __forceinline__ int dpp_add_i(int x) {
  int s = __builtin_amdgcn_update_dpp(0, x, CTRL, RM, 0xF, false);
  return x + s;
}
template <int CTRL, int RM>
__device__ __forceinline__ int dpp_max_i(int x) {
  int s = __builtin_amdgcn_update_dpp(0, x, CTRL, RM, 0xF, false);
  return x > s ? x : s;
}
__device__ __forceinline__ float wscan64_add(float x) {
  x = dpp_add_f<0x111, 0xF>(x); x = dpp_add_f<0x112, 0xF>(x);
  x = dpp_add_f<0x114, 0xF>(x); x = dpp_add_f<0x118, 0xF>(x);
  x = dpp_add_f<0x142, 0xA>(x); x = dpp_add_f<0x143, 0xC>(x);
  return x;
}
__device__ __forceinline__ int wscan64_addi(int x) {
  x = dpp_add_i<0x111, 0xF>(x); x = dpp_add_i<0x112, 0xF>(x);
  x = dpp_add_i<0x114, 0xF>(x); x = dpp_add_i<0x118, 0xF>(x);
  x = dpp_add_i<0x142, 0xA>(x); x = dpp_add_i<0x143, 0xC>(x);
  return x;
}
__device__ __forceinline__ int wscan64_max(int x) {
  x = dpp_max_i<0x111, 0xF>(x); x = dpp_max_i<0x112, 0xF>(x);
  x = dpp_max_i<0x114, 0xF>(x); x = dpp_max_i<0x118, 0xF>(x);
  x = dpp_max_i<0x142, 0xA>(x); x = dpp_max_i<0x143, 0xC>(x);
  return x;
}
__device__ __forceinline__ float rscan16_add(float x) {
  x = dpp_add_f<0x111, 0xF>(x); x = dpp_add_f<0x112, 0xF>(x);
  x = dpp_add_f<0x114, 0xF>(x); x = dpp_add_f<0x118, 0xF>(x);
  return x;
}
__device__ __forceinline__ int rscan16_addi(int x) {
  x = dpp_add_i<0x111, 0xF>(x); x = dpp_add_i<0x112, 0xF>(x);
  x = dpp_add_i<0x114, 0xF>(x); x = dpp_add_i<0x118, 0xF>(x);
  return x;
}
__device__ __forceinline__ int rscan16_max(int x) {
  x = dpp_max_i<0x111, 0xF>(x); x = dpp_max_i<0x112, 0xF>(x);
  x = dpp_max_i<0x114, 0xF>(x); x = dpp_max_i<0x118, 0xF>(x);
  return x;
}
__device__ __forceinline__ float readlane_f(float v, int l) {
  return __int_as_float(__builtin_amdgcn_readlane(__float_as_int(v), l));
}

// ---------------------------------------------------------------------------
// Transpose z [KP][TSTEPS] -> zT [TSTEPS][KP].
// ---------------------------------------------------------------------------
__global__ void transpose_k(const float* __restrict__ in, float* __restrict__ out) {
  __shared__ float tile[32][33];
  const int c0 = blockIdx.x * 32;
  const int r0 = blockIdx.y * 32;
  const int tx = threadIdx.x;
  const int ty = threadIdx.y;
#pragma unroll
  for (int i = 0; i < 32; i += 8)
    tile[ty + i][tx] = in[(size_t)(r0 + ty + i) * TSTEPS + c0 + tx];
  __syncthreads();
#pragma unroll
  for (int i = 0; i < 32; i += 8)
    out[(size_t)(c0 + ty + i) * KP + r0 + tx] = tile[tx][ty + i];
}

// ---------------------------------------------------------------------------
// One-time per-step bucket sort of u: produces sorted su[t][K], per-slot rank
// rank[t][k], and bucket-start table L_u[t][b] (exclusive prefix of histogram).
// Bucket mapping min((int)(u*NBF), NBUCK-1) matches the scan kernel exactly.
// ---------------------------------------------------------------------------
__global__ __launch_bounds__(BLOCK) void sortu_k(const float* __restrict__ u,
                                                 float* __restrict__ su,
                                                 unsigned short* __restrict__ rnk,
                                                 unsigned short* __restrict__ lu) {
  __shared__ int hist[NBUCK];
  __shared__ float sval[KP];
  __shared__ unsigned short sidx[KP];
  __shared__ int redi[NWAVES];
  const int t = blockIdx.x;
  const int tid = threadIdx.x;
  const int lane = tid & 63;
  const int wid = tid >> 6;
  const int kbase = tid * PT;

  float uv[PT];
  {
    float4 a = *(const float4*)(u + (size_t)t * KP + kbase);
    float4 b = *(const float4*)(u + (size_t)t * KP + kbase + 4);
    uv[0] = a.x; uv[1] = a.y; uv[2] = a.z; uv[3] = a.w;
    uv[4] = b.x; uv[5] = b.y; uv[6] = b.z; uv[7] = b.w;
  }
  int bj[PT];
#pragma unroll
  for (int j = 0; j < PT; ++j) {
    int b = (int)(uv[j] * NBF);
    bj[j] = b > NBUCK - 1 ? NBUCK - 1 : b;
  }
  {
    int4 z4; z4.x = z4.y = z4.z = z4.w = 0;
    *(int4*)(hist + kbase) = z4;
    *(int4*)(hist + kbase + 4) = z4;
  }
  __syncthreads();
#pragma unroll
  for (int j = 0; j < PT; ++j) atomicAdd(&hist[bj[j]], 1);
  __syncthreads();

  int4 ha = *(const int4*)(hist + kbase);
  int4 hb = *(const int4*)(hist + kbase + 4);
  int c0 = ha.x, c1 = c0 + ha.y, c2 = c1 + ha.z, c3 = c2 + ha.w;
  int c4 = c3 + hb.x, c5 = c4 + hb.y, c6 = c5 + hb.z, c7 = c6 + hb.w;
  int wincl = wscan64_addi(c7);
  int wexcl = wincl - c7;  // exact (ints)
  if (lane == 63) redi[wid] = wincl;
  __syncthreads();
  int v16 = rscan16_addi(redi[lane & 15]);
  int cp = wid ? __builtin_amdgcn_readlane(v16, wid - 1) : 0;
  int base = cp + wexcl;
  int ex[PT];
  ex[0] = base; ex[1] = base + c0; ex[2] = base + c1; ex[3] = base + c2;
  ex[4] = base + c3; ex[5] = base + c4; ex[6] = base + c5; ex[7] = base + c6;
  {
    int p0 = (ex[0] & 0xffff) | (ex[1] << 16);
    int p1 = (ex[2] & 0xffff) | (ex[3] << 16);
    int p2 = (ex[4] & 0xffff) | (ex[5] << 16);
    int p3 = (ex[6] & 0xffff) | (ex[7] << 16);
    int4 pk; pk.x = p0; pk.y = p1; pk.z = p2; pk.w = p3;
    *(int4*)(lu + (size_t)t * RS_LU + kbase) = pk;  // 16B aligned
  }
  {
    int4 pa; pa.x = ex[0]; pa.y = ex[1]; pa.z = ex[2]; pa.w = ex[3];
    int4 pb; pb.x = ex[4]; pb.y = ex[5]; pb.z = ex[6]; pb.w = ex[7];
    *(int4*)(hist + kbase) = pa;  // running placement pointers
    *(int4*)(hist + kbase + 4) = pb;
  }
  __syncthreads();
#pragma unroll
  for (int j = 0; j < PT; ++j) {
    int pos = atomicAdd(&hist[bj[j]], 1);
    sval[pos] = uv[j];
    sidx[pos] = (unsigned short)(kbase + j);
  }
  __syncthreads();
  // in-bucket insertion sort (buckets are Poisson(1)-sized; one-time cost)
  for (int bb = tid; bb < NBUCK; bb += BLOCK) {
    int s0 = bb ? hist[bb - 1] : 0;  // end of prev bucket == start of this one
    int e0 = hist[bb];
    for (int m = s0 + 1; m < e0; ++m) {
      float v = sval[m];
      unsigned short ix = sidx[m];
      int p = m - 1;
      while (p >= s0 && sval[p] > v) {
        sval[p + 1] = sval[p];
        sidx[p + 1] = sidx[p];
        --p;
      }
      sval[p + 1] = v;
      sidx[p + 1] = ix;
    }
  }
  __syncthreads();
  {
    float4 a, b;
    a.x = sval[kbase + 0]; a.y = sval[kbase + 1]; a.z = sval[kbase + 2]; a.w = sval[kbase + 3];
    b.x = sval[kbase + 4]; b.y = sval[kbase + 5]; b.z = sval[kbase + 6]; b.w = sval[kbase + 7];
    *(float4*)(su + (size_t)t * KP + kbase) = a;
    *(float4*)(su + (size_t)t * KP + kbase + 4) = b;
  }
#pragma unroll
  for (int j = 0; j < PT; ++j)
    rnk[(size_t)t * KP + sidx[kbase + j]] = (unsigned short)(kbase + j);
}

// ---------------------------------------------------------------------------
// Tier-A persistent scan: rank inversion. Per step: weights+scan -> cvn ->
// upper_bound into UNIFORM su (Poisson windows, <=4 rounds) -> scatter P
// (atomicMax, step-tagged) -> max-scan fill + topfix -> idx = P[rank] -> gather.
// 4 barriers/step, all phases data-independent.
// ---------------------------------------------------------------------------
__global__ __launch_bounds__(BLOCK) void smc_scan2(const float* __restrict__ x,
                                                   const float* __restrict__ w0,
                                                   const float* __restrict__ zsrc,
                                                   const float* __restrict__ su_g,
                                                   const unsigned short* __restrict__ rk_g,
                                                   const unsigned short* __restrict__ lu_g,
                                                   float* __restrict__ out) {
  extern __shared__ float sm[];
  float* wbufA = sm;                                   // KP
  float* wbufB = sm + KP;                              // KP
  float* su_s = sm + 2 * KP;                           // KP+8 (pad for frozen probes)
  int* P_s = (int*)(su_s + KP + 8);                    // KP+8 (rank -> tagged idx)
  unsigned short* Lu_s = (unsigned short*)(P_s + KP + 8);  // KP+16 u16
  float* redF = (float*)(Lu_s + KP + 16);              // NWAVES
  int* redI = (int*)(redF + NWAVES);                   // NWAVES
  int* bcI = redI + NWAVES;                            // 4

  const int tid = threadIdx.x;
  const int lane = tid & 63;
  const int wid = tid >> 6;
  const int kbase = tid * PT;

  float* wcur = wbufA;
  float* wnxt = wbufB;

  for (int i = tid; i < KP + 8; i += BLOCK) P_s[i] = 0;
  if (tid == 0) Lu_s[KP] = (unsigned short)KP;  // sentinel, constant

  float wv[PT];
  {
    float4 a = *(const float4*)(w0 + kbase);
    float4 b = *(const float4*)(w0 + kbase + 4);
    wv[0] = a.x; wv[1] = a.y; wv[2] = a.z; wv[3] = a.w;
    wv[4] = b.x; wv[5] = b.y; wv[6] = b.z; wv[7] = b.w;
    *(float4*)(wcur + kbase) = a;
    *(float4*)(wcur + kbase + 4) = b;
  }

  // Prefetch registers for step 0.
  float4 zna, znb, sna, snb;
  int4 lun, rkn;
  float xt_next = x[0];
  zna = *(const float4*)(zsrc + kbase);
  znb = *(const float4*)(zsrc + kbase + 4);
  sna = *(const float4*)(su_g + kbase);
  snb = *(const float4*)(su_g + kbase + 4);
  lun = *(const int4*)(lu_g + kbase);
  rkn = *(const int4*)(rk_g + kbase);
  __syncthreads();

  float acc = 0.f;

  for (int t = 0; t < TSTEPS; ++t) {
    // ---- stage su/Lu for step t (from prefetch regs), keep z/rank copies.
    *(float4*)(su_s + kbase) = sna;
    *(float4*)(su_s + kbase + 4) = snb;
    *(int4*)(Lu_s + kbase) = lun;  // 8 packed u16, 16B aligned
    float zv[PT];
    zv[0] = zna.x; zv[1] = zna.y; zv[2] = zna.z; zv[3] = zna.w;
    zv[4] = znb.x; zv[5] = znb.y; zv[6] = znb.z; zv[7] = znb.w;
    const int4 rkc = rkn;
    const float xt = xt_next;

    // ---- prefetch step t+1.
    if (t + 1 < TSTEPS) {
      xt_next = x[t + 1];
      const size_t ro = (size_t)(t + 1) * KP + kbase;
      zna = *(const float4*)(zsrc + ro);
      znb = *(const float4*)(zsrc + ro + 4);
      sna = *(const float4*)(su_g + ro);
      snb = *(const float4*)(su_g + ro + 4);
      lun = *(const int4*)(lu_g + (size_t)(t + 1) * RS_LU + kbase);
      rkn = *(const int4*)(rk_g + ro);
    }

    // ---- A: weights, exp (fp32 range suffices: w is a permutation of w0),
    // thread-local inclusive scan, DPP wave scan.
    float s[PT];
    float run = 0.f;
#pragma unroll
    for (int j = 0; j < PT; ++j) {
      float d = zv[j] - wv[j];
      float lw = fmaf(xt, zv[j], -0.5f * d * d);
      run += __expf(lw);
      s[j] = run;
    }
    const float wincl = wscan64_add(run);
    const float wexcl = wincl - run;
    if (lane == 63) redF[wid] = wincl;
    __syncthreads();  // B1

    // ---- B: cross-wave scan, normalized cvn.
    float v16 = rscan16_add(redF[lane & 15]);
    const float total = readlane_f(v16, 15);
    const float wpre = wid ? readlane_f(v16, wid - 1) : 0.f;
    const float base = wpre + wexcl;
    const float invT = 1.0f / total;
    if (tid == 0)
      acc += __logf(total) - 9.0109133472792886f   // log(K)
             - 0.5f * (1.8378770664093453f + xt * xt);
    float cvn[PT];
#pragma unroll
    for (int j = 0; j < PT; ++j) cvn[j] = (base + s[j]) * invT;

    // ---- C: R'_j = upper_bound(su, cvn_j) via L_u windows (Poisson(1) sized;
    // deterministic <=4 rounds regardless of weight skew).
    int lo[PT], len[PT];
    int anylen = 0;
#pragma unroll
    for (int j = 0; j < PT; ++j) {
      float fb = cvn[j] * NBF;
      int b = (int)fb;
      b = b > NBUCK - 1 ? NBUCK - 1 : b;
      b = b < 0 ? 0 : b;
      const int l = Lu_s[b];
      const int h = Lu_s[b + 1];
      lo[j] = l;
      len[j] = h - l;
      anylen |= len[j];
    }
    while (anylen) {
      anylen = 0;
#pragma unroll
      for (int j = 0; j < PT; ++j) {
        const int half = len[j] >> 1;
        const float v = su_s[lo[j] + half];
        const bool adv = (v <= cvn[j]) & (len[j] > 0);
        lo[j] = adv ? lo[j] + half + 1 : lo[j];
        len[j] = adv ? len[j] - half - 1 : half;
        anylen |= len[j];
      }
    }

    // ---- scatter P[R'_{i-1}] = i (step-tagged atomicMax; stale entries from
    // earlier steps have smaller tags and always lose).
    const int tagv = (t + 1) << 14;
    {
      int pr = __shfl_up(lo[PT - 1], 1);
      if (lane == 0) pr = 0x7fffffff;  // boundary handled by prev lane63
#pragma unroll
      for (int j = 0; j < PT; ++j) {
        if (lo[j] > pr) atomicMax(&P_s[pr], tagv | (kbase + j));
        pr = lo[j];
      }
      if (lane == 63 && tid != BLOCK - 1)
        atomicMax(&P_s[lo[PT - 1]], tagv | (kbase + PT));  // cross-thread boundary
      if (tid == BLOCK - 1) bcI[0] = lo[PT - 1];           // R'_{K-1}
    }
    __syncthreads();  // B2

    // ---- D1: local + wave max-scan over P (strip stale via tag).
    int4 pa = *(const int4*)(P_s + kbase);
    int4 pb = *(const int4*)(P_s + kbase + 4);
    const int e0 = pa.x >= tagv ? (pa.x & 16383) : 0;
    const int e1 = pa.y >= tagv ? (pa.y & 16383) : 0;
    const int e2 = pa.z >= tagv ? (pa.z & 16383) : 0;
    const int e3 = pa.w >= tagv ? (pa.w & 16383) : 0;
    const int e4 = pb.x >= tagv ? (pb.x & 16383) : 0;
    const int e5 = pb.y >= tagv ? (pb.y & 16383) : 0;
    const int e6 = pb.z >= tagv ? (pb.z & 16383) : 0;
    const int e7 = pb.w >= tagv ? (pb.w & 16383) : 0;
    int m1 = max(e0, e1), m2 = max(m1, e2), m3 = max(m2, e3);
    int m4 = max(m3, e4), m5 = max(m4, e5), m6 = max(m5, e6), m7 = max(m6, e7);
    const int mincl = wscan64_max(m7);
    int mexcl = __shfl_up(mincl, 1);
    if (lane == 0) mexcl = 0;
    if (lane == 63) redI[wid] = mincl;
    __syncthreads();  // B3

    // ---- D2: cross-wave max, finalize P in place (tagged) + topfix.
    {
      int mv = rscan16_max(redI[lane & 15]);
      const int crosspre = wid ? __builtin_amdgcn_readlane(mv, wid - 1) : 0;
      const int Rlast = bcI[0];
      int m = max(crosspre, mexcl);
      int4 oa, ob;
      m = max(m, e0); oa.x = tagv | ((kbase + 0 >= Rlast) ? (KP - 1) : m);
      m = max(m, e1); oa.y = tagv | ((kbase + 1 >= Rlast) ? (KP - 1) : m);
      m = max(m, e2); oa.z = tagv | ((kbase + 2 >= Rlast) ? (KP - 1) : m);
      m = max(m, e3); oa.w = tagv | ((kbase + 3 >= Rlast) ? (KP - 1) : m);
      m = max(m, e4); ob.x = tagv | ((kbase + 4 >= Rlast) ? (KP - 1) : m);
      m = max(m, e5); ob.y = tagv | ((kbase + 5 >= Rlast) ? (KP - 1) : m);
      m = max(m, e6); ob.z = tagv | ((kbase + 6 >= Rlast) ? (KP - 1) : m);
      m = max(m, e7); ob.w = tagv | ((kbase + 7 >= Rlast) ? (KP - 1) : m);
      *(int4*)(P_s + kbase) = oa;
      *(int4*)(P_s + kbase + 4) = ob;
    }
    __syncthreads();  // B4

    // ---- E: idx = P[rank_k] (direct read, NO search), gather, publish.
    {
      int r[PT];
      r[0] = rkc.x & 0xffff; r[1] = (rkc.x >> 16) & 0xffff;
      r[2] = rkc.y & 0xffff; r[3] = (rkc.y >> 16) & 0xffff;
      r[4] = rkc.z & 0xffff; r[5] = (rkc.z >> 16) & 0xffff;
      r[6] = rkc.w & 0xffff; r[7] = (rkc.w >> 16) & 0xffff;
      int idxv[PT];
#pragma unroll
      for (int j = 0; j < PT; ++j) idxv[j] = P_s[r[j]] & 16383;
      float nw[PT];
#pragma unroll
      for (int j = 0; j < PT; ++j) nw[j] = wcur[idxv[j]];
      float4 a, b;
      a.x = nw[0]; a.y = nw[1]; a.z = nw[2]; a.w = nw[3];
      b.x = nw[4]; b.y = nw[5]; b.z = nw[6]; b.w = nw[7];
      *(float4*)(wnxt + kbase) = a;
      *(float4*)(wnxt + kbase + 4) = b;
#pragma unroll
      for (int j = 0; j < PT; ++j) wv[j] = nw[j];
    }
    float* tmp = wcur; wcur = wnxt; wnxt = tmp;
    // next scatter is after next B1; phase-E reads are protected.
  }

  if (tid == 0) out[0] = acc;
}

// ---------------------------------------------------------------------------
// Tier-B fallback: proven round-6 kernel (bucketed binary search on cdf).
// ---------------------------------------------------------------------------
template <bool ZTRANS>
__global__ __launch_bounds__(BLOCK) void smc_scan(const float* __restrict__ x,
                                                  const float* __restrict__ w0,
                                                  const float* __restrict__ zsrc,
                                                  const float* __restrict__ u,
                                                  float* __restrict__ out) {
  extern __shared__ float sm[];
  float* wbufA = sm;
  float* wbufB = sm + KP;
  float* cdf_s = sm + 2 * KP;
  float* cend = cdf_s + KP;
  float* red = cend + BLOCK;
  int* redi = (int*)(red + NWAVES);
  int* bcI = redi + NWAVES;
  int* L_s = bcI + 4;

  const int tid = threadIdx.x;
  const int lane = tid & 63;
  const int wid = tid >> 6;
  const int kbase = tid * PT;

  float* wcur = wbufA;
  float* wnxt = wbufB;

  for (int i = tid; i < NBUCK; i += BLOCK) L_s[i] = 0;
  if (tid == 0) L_s[NBUCK] = KP - 1;

  float wv[PT];
  {
    float4 a = *(const float4*)(w0 + kbase);
    float4 b = *(const float4*)(w0 + kbase + 4);
    wv[0] = a.x; wv[1] = a.y; wv[2] = a.z; wv[3] = a.w;
    wv[4] = b.x; wv[5] = b.y; wv[6] = b.z; wv[7] = b.w;
    *(float4*)(wcur + kbase) = a;
    *(float4*)(wcur + kbase + 4) = b;
  }
  __syncthreads();

  float zn[PT], un[PT];
  float xt_next = x[0];
  if (ZTRANS) {
    float4 a = *(const float4*)(zsrc + kbase);
    float4 b = *(const float4*)(zsrc + kbase + 4);
    zn[0] = a.x; zn[1] = a.y; zn[2] = a.z; zn[3] = a.w;
    zn[4] = b.x; zn[5] = b.y; zn[6] = b.z; zn[7] = b.w;
  } else {
#pragma unroll
    for (int j = 0; j < PT; ++j) zn[j] = zsrc[(size_t)(kbase + j) * TSTEPS];
  }
  {
    float4 a = *(const float4*)(u + kbase);
    float4 b = *(const float4*)(u + kbase + 4);
    un[0] = a.x; un[1] = a.y; un[2] = a.z; un[3] = a.w;
    un[4] = b.x; un[5] = b.y; un[6] = b.z; un[7] = b.w;
  }

  float acc = 0.f;

  for (int t = 0; t < TSTEPS; ++t) {
    float zv[PT], uv[PT];
#pragma unroll
    for (int j = 0; j < PT; ++j) { zv[j] = zn[j]; uv[j] = un[j]; }
    const float xt = xt_next;

    if (t + 1 < TSTEPS) {
      xt_next = x[t + 1];
      if (ZTRANS) {
        float4 a = *(const float4*)(zsrc + (size_t)(t + 1) * KP + kbase);
        float4 b = *(const float4*)(zsrc + (size_t)(t + 1) * KP + kbase + 4);
        zn[0] = a.x; zn[1] = a.y; zn[2] = a.z; zn[3] = a.w;
        zn[4] = b.x; zn[5] = b.y; zn[6] = b.z; zn[7] = b.w;
      } else {
#pragma unroll
        for (int j = 0; j < PT; ++j)
          zn[j] = zsrc[(size_t)(kbase + j) * TSTEPS + t + 1];
      }
      float4 a = *(const float4*)(u + (size_t)(t + 1) * KP + kbase);
      float4 b = *(const float4*)(u + (size_t)(t + 1) * KP + kbase + 4);
      un[0] = a.x; un[1] = a.y; un[2] = a.z; un[3] = a.w;
      un[4] = b.x; un[5] = b.y; un[6] = b.z; un[7] = b.w;
    }

    float s[PT];
    float run = 0.f;
#pragma unroll
    for (int j = 0; j < PT; ++j) {
      float d = zv[j] - wv[j];
      float lw = fmaf(xt, zv[j], -0.5f * d * d);
      run += __expf(lw);
      s[j] = run;
    }
    const float wincl = wscan64_add(run);
    const float wexcl = wincl - run;
    if (lane == 63) red[wid] = wincl;
    __syncthreads();

    float v16 = rscan16_add(red[lane & 15]);
    const float total = readlane_f(v16, 15);
    const float wpre = wid ? readlane_f(v16, wid - 1) : 0.f;
    const float base = wpre + wexcl;
    const float invT = 1.0f / total;

    float cvn[PT];
#pragma unroll
    for (int j = 0; j < PT; ++j) cvn[j] = (base + s[j]) * invT;
    {
      float4 a, b;
      a.x = cvn[0]; a.y = cvn[1]; a.z = cvn[2]; a.w = cvn[3];
      b.x = cvn[4]; b.y = cvn[5]; b.z = cvn[6]; b.w = cvn[7];
      *(float4*)(cdf_s + kbase) = a;
      *(float4*)(cdf_s + kbase + 4) = b;
    }
    cend[tid] = cvn[PT - 1];
    if (tid == BLOCK - 1) bcI[0] = (int)(cvn[PT - 1] * NBF);
    {
      int4 z4; z4.x = z4.y = z4.z = z4.w = 0;
      *(int4*)(L_s + kbase) = z4;
      *(int4*)(L_s + kbase + 4) = z4;
    }
    if (tid == 0)
      acc += __logf(total) - 9.0109133472792886f
             - 0.5f * (1.8378770664093453f + xt * xt);
    __syncthreads();

    {
      const float cprev = tid ? cend[tid - 1] : 0.f;
      int flo = (int)(cprev * NBF);
#pragma unroll
      for (int j = 0; j < PT; ++j) {
        int fhi = (int)(cvn[j] * NBF);
        if (fhi > NBUCK - 1) fhi = NBUCK - 1;
        if (fhi > flo) L_s[flo + 1] = kbase + j;
        flo = fhi;
      }
    }
    __syncthreads();

    int4 ra = *(const int4*)(L_s + kbase);
    int4 rb = *(const int4*)(L_s + kbase + 4);
    int c1 = max(ra.x, ra.y);
    int c2 = max(c1, ra.z);
    int c3 = max(c2, ra.w);
    int c4 = max(c3, rb.x);
    int c5 = max(c4, rb.y);
    int c6 = max(c5, rb.z);
    int c7 = max(c6, rb.w);
    const int mincl = wscan64_max(c7);
    int mexcl = __shfl_up(mincl, 1);
    if (lane == 0) mexcl = 0;
    if (lane == 63) redi[wid] = mincl;
    __syncthreads();

    {
      int mv = rscan16_max(redi[lane & 15]);
      const int crosspre = wid ? __builtin_amdgcn_readlane(mv, wid - 1) : 0;
      const int fhiLast = bcI[0];
      int m = max(crosspre, mexcl);
      int4 oa, ob;
      m = max(m, ra.x); oa.x = (kbase + 0 > fhiLast) ? (KP - 1) : m;
      m = max(m, ra.y); oa.y = (kbase + 1 > fhiLast) ? (KP - 1) : m;
      m = max(m, ra.z); oa.z = (kbase + 2 > fhiLast) ? (KP - 1) : m;
      m = max(m, ra.w); oa.w = (kbase + 3 > fhiLast) ? (KP - 1) : m;
      m = max(m, rb.x); ob.x = (kbase + 4 > fhiLast) ? (KP - 1) : m;
      m = max(m, rb.y); ob.y = (kbase + 5 > fhiLast) ? (KP - 1) : m;
      m = max(m, rb.z); ob.z = (kbase + 6 > fhiLast) ? (KP - 1) : m;
      m = max(m, rb.w); ob.w = (kbase + 7 > fhiLast) ? (KP - 1) : m;
      *(int4*)(L_s + kbase) = oa;
      *(int4*)(L_s + kbase + 4) = ob;
    }
    __syncthreads();

    int lo[PT], len[PT];
    float tg[PT];
    int anylen = 0;
#pragma unroll
    for (int j = 0; j < PT; ++j) {
      tg[j] = uv[j];
      const float fb = uv[j] * NBF;
      int b = (int)fb;
      b = min(b, NBUCK - 1);
      const int i0 = L_s[b];
      const int i1 = L_s[b + 1];
      lo[j] = i0;
      len[j] = i1 - i0;
      anylen |= len[j];
    }
    while (anylen) {
      anylen = 0;
#pragma unroll
      for (int j = 0; j < PT; ++j) {
        const int half = len[j] >> 1;
        const float c = cdf_s[lo[j] + half];
        const bool adv = (c < tg[j]) & (len[j] > 0);
        lo[j] = adv ? lo[j] + half + 1 : lo[j];
        len[j] = adv ? len[j] - half - 1 : half;
        anylen |= len[j];
      }
    }

    float nw[PT];
#pragma unroll
    for (int j = 0; j < PT; ++j) nw[j] = wcur[lo[j]];
    {
      float4 a, b;
      a.x = nw[0]; a.y = nw[1]; a.z = nw[2]; a.w = nw[3];
      b.x = nw[4]; b.y = nw[5]; b.z = nw[6]; b.w = nw[7];
      *(float4*)(wnxt + kbase) = a;
      *(float4*)(wnxt + kbase + 4) = b;
    }
#pragma unroll
    for (int j = 0; j < PT; ++j) wv[j] = nw[j];
    float* tmp = wcur; wcur = wnxt; wnxt = tmp;
  }

  if (tid == 0) out[0] = acc;
}

// ---------------------------------------------------------------------------
extern "C" void kernel_launch(void* const* d_in, const int* in_sizes, int n_in,
                              void* d_out, int out_size, void* d_ws, size_t ws_size,
                              hipStream_t stream) {
  const float* x = (const float*)d_in[0];   // [T]
  const float* w0 = (const float*)d_in[1];  // [K]
  const float* z = (const float*)d_in[2];   // [K,T]
  const float* u = (const float*)d_in[3];   // [T,K]
  float* out = (float*)d_out;

  const size_t SZ_ZT = (size_t)KP * TSTEPS * sizeof(float);      // 128 MiB
  const size_t OFF_SU = SZ_ZT;
  const size_t SZ_SU = SZ_ZT;                                    // 128 MiB
  const size_t OFF_RK = OFF_SU + SZ_SU;
  const size_t SZ_RK = (size_t)KP * TSTEPS * 2;                  // 64 MiB
  const size_t OFF_LU = OFF_RK + SZ_RK;
  const size_t SZ_LU = (size_t)TSTEPS * RS_LU * 2;               // ~64 MiB
  const size_t FULL = OFF_LU + SZ_LU;                            // ~403 MB

  if (ws_size >= FULL) {
    // Tier A: rank-inversion path.
    char* ws = (char*)d_ws;
    float* zT = (float*)ws;
    float* su = (float*)(ws + OFF_SU);
    unsigned short* rk = (unsigned short*)(ws + OFF_RK);
    unsigned short* lu = (unsigned short*)(ws + OFF_LU);
    transpose_k<<<dim3(TSTEPS / 32, KP / 32), dim3(32, 8), 0, stream>>>(z, zT);
    sortu_k<<<TSTEPS, BLOCK, 0, stream>>>(u, su, rk, lu);
    const size_t shmem2 =
        ((size_t)KP * 2 + (KP + 8) /*su*/ + (KP + 8) /*P*/) * sizeof(float) +
        (size_t)(KP + 16) * sizeof(unsigned short) +
        (size_t)(NWAVES) * sizeof(float) + (size_t)(NWAVES + 4) * sizeof(int);
    smc_scan2<<<1, BLOCK, shmem2, stream>>>(x, w0, zT, su, rk, lu, out);
  } else {
    // Tier B/C: proven round-6 kernel.
    const size_t shmem =
        (size_t)(3 * KP + BLOCK + NWAVES + NWAVES + 4 + NBUCK + 1) * sizeof(float);
    if (ws_size >= SZ_ZT) {
      float* zT = (float*)d_ws;
      transpose_k<<<dim3(TSTEPS / 32, KP / 32), dim3(32, 8), 0, stream>>>(z, zT);
      smc_scan<true><<<1, BLOCK, shmem, stream>>>(x, w0, zT, u, out);
    } else {
      smc_scan<false><<<1, BLOCK, shmem, stream>>>(x, w0, z, u, out);
    }
  }
}

// Round 9
// 23185.741 us; speedup vs baseline: 1.4897x; 1.4897x over previous
//
#include <hip/hip_runtime.h>
#include <math.h>

#define KP 8192
#define TSTEPS 4096
#define BLOCK 1024
#define PT 8                 // particles per thread
#define NWAVES 16
#define NBUCK 8192
#define NBF 8192.0f
#define MSTEPS 16            // merge steps per thread = 2*KP/BLOCK
#define F_INF __int_as_float(0x7f800000)

// ---------------- DPP wave-scan helpers (pure VALU, no LDS pipe) ----------------
template <int CTRL, int RM>
__device__ __forceinline__ float dpp_add_f(float x) {
  int s = __builtin_amdgcn_update_dpp(0, __float_as_int(x), CTRL, RM, 0xF, false);
  return x + __int_as_float(s);
}
template <int CTRL, int RM>
__device__ __forceinline__ int dpp_add_i(int x) {
  int s = __builtin_amdgcn_update_dpp(0, x, CTRL, RM, 0xF, false);
  return x + s;
}
template <int CTRL, int RM>
__device__ __forceinline__ int dpp_max_i(int x) {
  int s = __builtin_amdgcn_update_dpp(0, x, CTRL, RM, 0xF, false);
  return x > s ? x : s;
}
__device__ __forceinline__ float wscan64_add(float x) {
  x = dpp_add_f<0x111, 0xF>(x); x = dpp_add_f<0x112, 0xF>(x);
  x = dpp_add_f<0x114, 0xF>(x); x = dpp_add_f<0x118, 0xF>(x);
  x = dpp_add_f<0x142, 0xA>(x); x = dpp_add_f<0x143, 0xC>(x);
  return x;
}
__device__ __forceinline__ int wscan64_addi(int x) {
  x = dpp_add_i<0x111, 0xF>(x); x = dpp_add_i<0x112, 0xF>(x);
  x = dpp_add_i<0x114, 0xF>(x); x = dpp_add_i<0x118, 0xF>(x);
  x = dpp_add_i<0x142, 0xA>(x); x = dpp_add_i<0x143, 0xC>(x);
  return x;
}
__device__ __forceinline__ int wscan64_max(int x) {
  x = dpp_max_i<0x111, 0xF>(x); x = dpp_max_i<0x112, 0xF>(x);
  x = dpp_max_i<0x114, 0xF>(x); x = dpp_max_i<0x118, 0xF>(x);
  x = dpp_max_i<0x142, 0xA>(x); x = dpp_max_i<0x143, 0xC>(x);
  return x;
}
__device__ __forceinline__ float rscan16_add(float x) {
  x = dpp_add_f<0x111, 0xF>(x); x = dpp_add_f<0x112, 0xF>(x);
  x = dpp_add_f<0x114, 0xF>(x); x = dpp_add_f<0x118, 0xF>(x);
  return x;
}
__device__ __forceinline__ int rscan16_addi(int x) {
  x = dpp_add_i<0x111, 0xF>(x); x = dpp_add_i<0x112, 0xF>(x);
  x = dpp_add_i<0x114, 0xF>(x); x = dpp_add_i<0x118, 0xF>(x);
  return x;
}
__device__ __forceinline__ int rscan16_max(int x) {
  x = dpp_max_i<0x111, 0xF>(x); x = dpp_max_i<0x112, 0xF>(x);
  x = dpp_max_i<0x114, 0xF>(x); x = dpp_max_i<0x118, 0xF>(x);
  return x;
}
__device__ __forceinline__ float readlane_f(float v, int l) {
  return __int_as_float(__builtin_amdgcn_readlane(__float_as_int(v), l));
}

// ---------------------------------------------------------------------------
// Transpose z [KP][TSTEPS] -> zT [TSTEPS][KP].
// ---------------------------------------------------------------------------
__global__ void transpose_k(const float* __restrict__ in, float* __restrict__ out) {
  __shared__ float tile[32][33];
  const int c0 = blockIdx.x * 32;
  const int r0 = blockIdx.y * 32;
  const int tx = threadIdx.x;
  const int ty = threadIdx.y;
#pragma unroll
  for (int i = 0; i < 32; i += 8)
    tile[ty + i][tx] = in[(size_t)(r0 + ty + i) * TSTEPS + c0 + tx];
  __syncthreads();
#pragma unroll
  for (int i = 0; i < 32; i += 8)
    out[(size_t)(c0 + ty + i) * KP + r0 + tx] = tile[tx][ty + i];
}

// ---------------------------------------------------------------------------
// One-time per-step bucket sort of u: sorted su[t][K] + per-slot rank rank[t][k].
// ---------------------------------------------------------------------------
__global__ __launch_bounds__(BLOCK) void sortu_k(const float* __restrict__ u,
                                                 float* __restrict__ su,
                                                 unsigned short* __restrict__ rnk) {
  __shared__ int hist[NBUCK];
  __shared__ float sval[KP];
  __shared__ unsigned short sidx[KP];
  __shared__ int redi[NWAVES];
  const int t = blockIdx.x;
  const int tid = threadIdx.x;
  const int lane = tid & 63;
  const int wid = tid >> 6;
  const int kbase = tid * PT;

  float uv[PT];
  {
    float4 a = *(const float4*)(u + (size_t)t * KP + kbase);
    float4 b = *(const float4*)(u + (size_t)t * KP + kbase + 4);
    uv[0] = a.x; uv[1] = a.y; uv[2] = a.z; uv[3] = a.w;
    uv[4] = b.x; uv[5] = b.y; uv[6] = b.z; uv[7] = b.w;
  }
  int bj[PT];
#pragma unroll
  for (int j = 0; j < PT; ++j) {
    int b = (int)(uv[j] * NBF);
    bj[j] = b > NBUCK - 1 ? NBUCK - 1 : b;
  }
  {
    int4 z4; z4.x = z4.y = z4.z = z4.w = 0;
    *(int4*)(hist + kbase) = z4;
    *(int4*)(hist + kbase + 4) = z4;
  }
  __syncthreads();
#pragma unroll
  for (int j = 0; j < PT; ++j) atomicAdd(&hist[bj[j]], 1);
  __syncthreads();

  int4 ha = *(const int4*)(hist + kbase);
  int4 hb = *(const int4*)(hist + kbase + 4);
  int c0 = ha.x, c1 = c0 + ha.y, c2 = c1 + ha.z, c3 = c2 + ha.w;
  int c4 = c3 + hb.x, c5 = c4 + hb.y, c6 = c5 + hb.z, c7 = c6 + hb.w;
  int wincl = wscan64_addi(c7);
  int wexcl = wincl - c7;
  if (lane == 63) redi[wid] = wincl;
  __syncthreads();
  int v16 = rscan16_addi(redi[lane & 15]);
  int cp = wid ? __builtin_amdgcn_readlane(v16, wid - 1) : 0;
  int base = cp + wexcl;
  {
    int4 pa; pa.x = base; pa.y = base + c0; pa.z = base + c1; pa.w = base + c2;
    int4 pb; pb.x = base + c3; pb.y = base + c4; pb.z = base + c5; pb.w = base + c6;
    *(int4*)(hist + kbase) = pa;  // running placement pointers
    *(int4*)(hist + kbase + 4) = pb;
  }
  __syncthreads();
#pragma unroll
  for (int j = 0; j < PT; ++j) {
    int pos = atomicAdd(&hist[bj[j]], 1);
    sval[pos] = uv[j];
    sidx[pos] = (unsigned short)(kbase + j);
  }
  __syncthreads();
  // in-bucket insertion sort (Poisson(1) buckets; one-time cost)
  for (int bb = tid; bb < NBUCK; bb += BLOCK) {
    int s0 = bb ? hist[bb - 1] : 0;
    int e0 = hist[bb];
    for (int m = s0 + 1; m < e0; ++m) {
      float v = sval[m];
      unsigned short ix = sidx[m];
      int p = m - 1;
      while (p >= s0 && sval[p] > v) {
        sval[p + 1] = sval[p];
        sidx[p + 1] = sidx[p];
        --p;
      }
      sval[p + 1] = v;
      sidx[p + 1] = ix;
    }
  }
  __syncthreads();
  {
    float4 a, b;
    a.x = sval[kbase + 0]; a.y = sval[kbase + 1]; a.z = sval[kbase + 2]; a.w = sval[kbase + 3];
    b.x = sval[kbase + 4]; b.y = sval[kbase + 5]; b.z = sval[kbase + 6]; b.w = sval[kbase + 7];
    *(float4*)(su + (size_t)t * KP + kbase) = a;
    *(float4*)(su + (size_t)t * KP + kbase + 4) = b;
  }
#pragma unroll
  for (int j = 0; j < PT; ++j)
    rnk[(size_t)t * KP + sidx[kbase + j]] = (unsigned short)(kbase + j);
}

// ---------------------------------------------------------------------------
// Tier-A persistent scan: MERGE-PATH resampling.
// lower_bound(cdf, su[j]) for all sorted j == merge of cdf (A) and su (B)
// with rule: consume A while A[i]<B[j], else emit ans[j]=i. Merge-path
// splits the 2K steps exactly evenly: per thread one diagonal binary search
// (<=13 rounds, data-INDEPENDENT) + exactly MSTEPS merge steps. Emit writes
// the w VALUE (clipped gather folded in): P[j] = w[min(i,K-1)].
// Resample: wv[k] = P[rank[k]]. 3 barriers/step, no atomics, no skew tail.
// ---------------------------------------------------------------------------
__global__ __launch_bounds__(BLOCK) void smc_scan3(const float* __restrict__ x,
                                                   const float* __restrict__ w0,
                                                   const float* __restrict__ zsrc,
                                                   const float* __restrict__ su_g,
                                                   const unsigned short* __restrict__ rk_g,
                                                   float* __restrict__ out) {
  extern __shared__ float sm[];
  float* w_s   = sm;                 // KP   particle values
  float* cdf_s = sm + KP;            // KP+8 normalized cdf, sentinel +inf at [KP]
  float* su_s  = cdf_s + KP + 8;     // KP+8 sorted uniforms, sentinel +inf at [KP]
  float* P_s   = su_s + KP + 8;      // KP   rank -> resampled w value
  float* redF  = P_s + KP;           // NWAVES

  const int tid = threadIdx.x;
  const int lane = tid & 63;
  const int wid = tid >> 6;
  const int kbase = tid * PT;

  if (tid == 0) { cdf_s[KP] = F_INF; su_s[KP] = F_INF; }  // persistent sentinels

  float wv[PT];
  {
    float4 a = *(const float4*)(w0 + kbase);
    float4 b = *(const float4*)(w0 + kbase + 4);
    wv[0] = a.x; wv[1] = a.y; wv[2] = a.z; wv[3] = a.w;
    wv[4] = b.x; wv[5] = b.y; wv[6] = b.z; wv[7] = b.w;
    *(float4*)(w_s + kbase) = a;
    *(float4*)(w_s + kbase + 4) = b;
  }

  // Prefetch registers for step 0.
  float4 zna, znb, sna, snb;
  int4 rkn;
  float xt_next = x[0];
  zna = *(const float4*)(zsrc + kbase);
  znb = *(const float4*)(zsrc + kbase + 4);
  sna = *(const float4*)(su_g + kbase);
  snb = *(const float4*)(su_g + kbase + 4);
  rkn = *(const int4*)(rk_g + kbase);

  float acc = 0.f;

  for (int t = 0; t < TSTEPS; ++t) {
    // ---- stage su for step t (su_s reads of step t-1 all finished pre-B3(t-1)).
    *(float4*)(su_s + kbase) = sna;
    *(float4*)(su_s + kbase + 4) = snb;
    float zv[PT];
    zv[0] = zna.x; zv[1] = zna.y; zv[2] = zna.z; zv[3] = zna.w;
    zv[4] = znb.x; zv[5] = znb.y; zv[6] = znb.z; zv[7] = znb.w;
    const int4 rkc = rkn;
    const float xt = xt_next;

    // ---- prefetch step t+1 (consumed next iteration; full step of slack).
    if (t + 1 < TSTEPS) {
      xt_next = x[t + 1];
      const size_t ro = (size_t)(t + 1) * KP + kbase;
      zna = *(const float4*)(zsrc + ro);
      znb = *(const float4*)(zsrc + ro + 4);
      sna = *(const float4*)(su_g + ro);
      snb = *(const float4*)(su_g + ro + 4);
      rkn = *(const int4*)(rk_g + ro);
    }

    // ---- A: weights, exp (fp32 range suffices: w is a permutation of w0),
    // thread-local inclusive scan, DPP wave scan.
    float s[PT];
    float run = 0.f;
#pragma unroll
    for (int j = 0; j < PT; ++j) {
      float d = zv[j] - wv[j];
      float lw = fmaf(xt, zv[j], -0.5f * d * d);
      run += __expf(lw);
      s[j] = run;
    }
    const float wincl = wscan64_add(run);
    const float wexcl = wincl - run;
    if (lane == 63) redF[wid] = wincl;
    __syncthreads();  // B1: redF + su staging + prev-step w_s writes visible

    // ---- B: cross-wave scan, normalized cdf write.
    float v16 = rscan16_add(redF[lane & 15]);
    const float total = readlane_f(v16, 15);
    const float wpre = wid ? readlane_f(v16, wid - 1) : 0.f;
    const float base = wpre + wexcl;
    const float invT = 1.0f / total;
    if (tid == 0)
      acc += __logf(total) - 9.0109133472792886f   // log(K)
             - 0.5f * (1.8378770664093453f + xt * xt);
    {
      float4 a, b;
      a.x = (base + s[0]) * invT; a.y = (base + s[1]) * invT;
      a.z = (base + s[2]) * invT; a.w = (base + s[3]) * invT;
      b.x = (base + s[4]) * invT; b.y = (base + s[5]) * invT;
      b.z = (base + s[6]) * invT; b.w = (base + s[7]) * invT;
      *(float4*)(cdf_s + kbase) = a;
      *(float4*)(cdf_s + kbase + 4) = b;
    }
    __syncthreads();  // B2: cdf_s visible

    // ---- C: merge-path. Diagonal d = tid*MSTEPS. Unique split i* =
    // smallest i in [max(0,d-K), min(d,K)] with cdf[i] >= su[d-1-i]
    // (strict-consume rule => emit-on-tie; predicate proven monotone).
    {
      const int d = tid * MSTEPS;
      int lo = d > KP ? d - KP : 0;
      int hi = d < KP ? d : KP;
      while (lo < hi) {
        const int m = (lo + hi) >> 1;          // m < hi <= min(d,K): both reads in range
        const float a = cdf_s[m];
        const float b = su_s[d - 1 - m];
        if (a >= b) hi = m; else lo = m + 1;
      }
      int i = lo;
      int j = d - lo;
      // exactly MSTEPS merge steps; sentinels stop the exhausted side.
      float av = cdf_s[i];
      float bv = su_s[j];
#pragma unroll 1
      for (int sme = 0; sme < MSTEPS; ++sme) {
        const bool cons = (av < bv);
        if (!cons) P_s[j] = w_s[i < KP ? i : KP - 1];  // emit: value, clip folded
        i += cons ? 1 : 0;
        j += cons ? 0 : 1;
        const float nv = cons ? cdf_s[i] : su_s[j];    // single select-address read
        av = cons ? nv : av;
        bv = cons ? bv : nv;
      }
    }
    __syncthreads();  // B3: P_s complete (every rank emitted exactly once)

    // ---- E: resample = P[rank], refresh registers + w_s for next step.
    {
      int r[PT];
      r[0] = rkc.x & 0xffff; r[1] = (rkc.x >> 16) & 0xffff;
      r[2] = rkc.y & 0xffff; r[3] = (rkc.y >> 16) & 0xffff;
      r[4] = rkc.z & 0xffff; r[5] = (rkc.z >> 16) & 0xffff;
      r[6] = rkc.w & 0xffff; r[7] = (rkc.w >> 16) & 0xffff;
#pragma unroll
      for (int j = 0; j < PT; ++j) wv[j] = P_s[r[j]];
      float4 a, b;
      a.x = wv[0]; a.y = wv[1]; a.z = wv[2]; a.w = wv[3];
      b.x = wv[4]; b.y = wv[5]; b.z = wv[6]; b.w = wv[7];
      *(float4*)(w_s + kbase) = a;      // read in next step's C (after B1,B2)
      *(float4*)(w_s + kbase + 4) = b;
    }
  }

  if (tid == 0) out[0] = acc;
}

// ---------------------------------------------------------------------------
// Tier-B fallback: proven round-6 kernel (bucketed binary search on cdf).
// ---------------------------------------------------------------------------
template <bool ZTRANS>
__global__ __launch_bounds__(BLOCK) void smc_scan(const float* __restrict__ x,
                                                  const float* __restrict__ w0,
                                                  const float* __restrict__ zsrc,
                                                  const float* __restrict__ u,
                                                  float* __restrict__ out) {
  extern __shared__ float sm[];
  float* wbufA = sm;
  float* wbufB = sm + KP;
  float* cdf_s = sm + 2 * KP;
  float* cend = cdf_s + KP;
  float* red = cend + BLOCK;
  int* redi = (int*)(red + NWAVES);
  int* bcI = redi + NWAVES;
  int* L_s = bcI + 4;

  const int tid = threadIdx.x;
  const int lane = tid & 63;
  const int wid = tid >> 6;
  const int kbase = tid * PT;

  float* wcur = wbufA;
  float* wnxt = wbufB;

  for (int i = tid; i < NBUCK; i += BLOCK) L_s[i] = 0;
  if (tid == 0) L_s[NBUCK] = KP - 1;

  float wv[PT];
  {
    float4 a = *(const float4*)(w0 + kbase);
    float4 b = *(const float4*)(w0 + kbase + 4);
    wv[0] = a.x; wv[1] = a.y; wv[2] = a.z; wv[3] = a.w;
    wv[4] = b.x; wv[5] = b.y; wv[6] = b.z; wv[7] = b.w;
    *(float4*)(wcur + kbase) = a;
    *(float4*)(wcur + kbase + 4) = b;
  }
  __syncthreads();

  float zn[PT], un[PT];
  float xt_next = x[0];
  if (ZTRANS) {
    float4 a = *(const float4*)(zsrc + kbase);
    float4 b = *(const float4*)(zsrc + kbase + 4);
    zn[0] = a.x; zn[1] = a.y; zn[2] = a.z; zn[3] = a.w;
    zn[4] = b.x; zn[5] = b.y; zn[6] = b.z; zn[7] = b.w;
  } else {
#pragma unroll
    for (int j = 0; j < PT; ++j) zn[j] = zsrc[(size_t)(kbase + j) * TSTEPS];
  }
  {
    float4 a = *(const float4*)(u + kbase);
    float4 b = *(const float4*)(u + kbase + 4);
    un[0] = a.x; un[1] = a.y; un[2] = a.z; un[3] = a.w;
    un[4] = b.x; un[5] = b.y; un[6] = b.z; un[7] = b.w;
  }

  float acc = 0.f;

  for (int t = 0; t < TSTEPS; ++t) {
    float zv[PT], uv[PT];
#pragma unroll
    for (int j = 0; j < PT; ++j) { zv[j] = zn[j]; uv[j] = un[j]; }
    const float xt = xt_next;

    if (t + 1 < TSTEPS) {
      xt_next = x[t + 1];
      if (ZTRANS) {
        float4 a = *(const float4*)(zsrc + (size_t)(t + 1) * KP + kbase);
        float4 b = *(const float4*)(zsrc + (size_t)(t + 1) * KP + kbase + 4);
        zn[0] = a.x; zn[1] = a.y; zn[2] = a.z; zn[3] = a.w;
        zn[4] = b.x; zn[5] = b.y; zn[6] = b.z; zn[7] = b.w;
      } else {
#pragma unroll
        for (int j = 0; j < PT; ++j)
          zn[j] = zsrc[(size_t)(kbase + j) * TSTEPS + t + 1];
      }
      float4 a = *(const float4*)(u + (size_t)(t + 1) * KP + kbase);
      float4 b = *(const float4*)(u + (size_t)(t + 1) * KP + kbase + 4);
      un[0] = a.x; un[1] = a.y; un[2] = a.z; un[3] = a.w;
      un[4] = b.x; un[5] = b.y; un[6] = b.z; un[7] = b.w;
    }

    float s[PT];
    float run = 0.f;
#pragma unroll
    for (int j = 0; j < PT; ++j) {
      float d = zv[j] - wv[j];
      float lw = fmaf(xt, zv[j], -0.5f * d * d);
      run += __expf(lw);
      s[j] = run;
    }
    const float wincl = wscan64_add(run);
    const float wexcl = wincl - run;
    if (lane == 63) red[wid] = wincl;
    __syncthreads();

    float v16 = rscan16_add(red[lane & 15]);
    const float total = readlane_f(v16, 15);
    const float wpre = wid ? readlane_f(v16, wid - 1) : 0.f;
    const float base = wpre + wexcl;
    const float invT = 1.0f / total;

    float cvn[PT];
#pragma unroll
    for (int j = 0; j < PT; ++j) cvn[j] = (base + s[j]) * invT;
    {
      float4 a, b;
      a.x = cvn[0]; a.y = cvn[1]; a.z = cvn[2]; a.w = cvn[3];
      b.x = cvn[4]; b.y = cvn[5]; b.z = cvn[6]; b.w = cvn[7];
      *(float4*)(cdf_s + kbase) = a;
      *(float4*)(cdf_s + kbase + 4) = b;
    }
    cend[tid] = cvn[PT - 1];
    if (tid == BLOCK - 1) bcI[0] = (int)(cvn[PT - 1] * NBF);
    {
      int4 z4; z4.x = z4.y = z4.z = z4.w = 0;
      *(int4*)(L_s + kbase) = z4;
      *(int4*)(L_s + kbase + 4) = z4;
    }
    if (tid == 0)
      acc += __logf(total) - 9.0109133472792886f
             - 0.5f * (1.8378770664093453f + xt * xt);
    __syncthreads();

    {
      const float cprev = tid ? cend[tid - 1] : 0.f;
      int flo = (int)(cprev * NBF);
#pragma unroll
      for (int j = 0; j < PT; ++j) {
        int fhi = (int)(cvn[j] * NBF);
        if (fhi > NBUCK - 1) fhi = NBUCK - 1;
        if (fhi > flo) L_s[flo + 1] = kbase + j;
        flo = fhi;
      }
    }
    __syncthreads();

    int4 ra = *(const int4*)(L_s + kbase);
    int4 rb = *(const int4*)(L_s + kbase + 4);
    int c1 = max(ra.x, ra.y);
    int c2 = max(c1, ra.z);
    int c3 = max(c2, ra.w);
    int c4 = max(c3, rb.x);
    int c5 = max(c4, rb.y);
    int c6 = max(c5, rb.z);
    int c7 = max(c6, rb.w);
    const int mincl = wscan64_max(c7);
    int mexcl = __shfl_up(mincl, 1);
    if (lane == 0) mexcl = 0;
    if (lane == 63) redi[wid] = mincl;
    __syncthreads();

    {
      int mv = rscan16_max(redi[lane & 15]);
      const int crosspre = wid ? __builtin_amdgcn_readlane(mv, wid - 1) : 0;
      const int fhiLast = bcI[0];
      int m = max(crosspre, mexcl);
      int4 oa, ob;
      m = max(m, ra.x); oa.x = (kbase + 0 > fhiLast) ? (KP - 1) : m;
      m = max(m, ra.y); oa.y = (kbase + 1 > fhiLast) ? (KP - 1) : m;
      m = max(m, ra.z); oa.z = (kbase + 2 > fhiLast) ? (KP - 1) : m;
      m = max(m, ra.w); oa.w = (kbase + 3 > fhiLast) ? (KP - 1) : m;
      m = max(m, rb.x); ob.x = (kbase + 4 > fhiLast) ? (KP - 1) : m;
      m = max(m, rb.y); ob.y = (kbase + 5 > fhiLast) ? (KP - 1) : m;
      m = max(m, rb.z); ob.z = (kbase + 6 > fhiLast) ? (KP - 1) : m;
      m = max(m, rb.w); ob.w = (kbase + 7 > fhiLast) ? (KP - 1) : m;
      *(int4*)(L_s + kbase) = oa;
      *(int4*)(L_s + kbase + 4) = ob;
    }
    __syncthreads();

    int lo[PT], len[PT];
    float tg[PT];
    int anylen = 0;
#pragma unroll
    for (int j = 0; j < PT; ++j) {
      tg[j] = uv[j];
      const float fb = uv[j] * NBF;
      int b = (int)fb;
      b = min(b, NBUCK - 1);
      const int i0 = L_s[b];
      const int i1 = L_s[b + 1];
      lo[j] = i0;
      len[j] = i1 - i0;
      anylen |= len[j];
    }
    while (anylen) {
      anylen = 0;
#pragma unroll
      for (int j = 0; j < PT; ++j) {
        const int half = len[j] >> 1;
        const float c = cdf_s[lo[j] + half];
        const bool adv = (c < tg[j]) & (len[j] > 0);
        lo[j] = adv ? lo[j] + half + 1 : lo[j];
        len[j] = adv ? len[j] - half - 1 : half;
        anylen |= len[j];
      }
    }

    float nw[PT];
#pragma unroll
    for (int j = 0; j < PT; ++j) nw[j] = wcur[lo[j]];
    {
      float4 a, b;
      a.x = nw[0]; a.y = nw[1]; a.z = nw[2]; a.w = nw[3];
      b.x = nw[4]; b.y = nw[5]; b.z = nw[6]; b.w = nw[7];
      *(float4*)(wnxt + kbase) = a;
      *(float4*)(wnxt + kbase + 4) = b;
    }
#pragma unroll
    for (int j = 0; j < PT; ++j) wv[j] = nw[j];
    float* tmp = wcur; wcur = wnxt; wnxt = tmp;
  }

  if (tid == 0) out[0] = acc;
}

// ---------------------------------------------------------------------------
extern "C" void kernel_launch(void* const* d_in, const int* in_sizes, int n_in,
                              void* d_out, int out_size, void* d_ws, size_t ws_size,
                              hipStream_t stream) {
  const float* x = (const float*)d_in[0];   // [T]
  const float* w0 = (const float*)d_in[1];  // [K]
  const float* z = (const float*)d_in[2];   // [K,T]
  const float* u = (const float*)d_in[3];   // [T,K]
  float* out = (float*)d_out;

  const size_t SZ_ZT = (size_t)KP * TSTEPS * sizeof(float);      // 128 MiB
  const size_t OFF_SU = SZ_ZT;
  const size_t SZ_SU = SZ_ZT;                                    // 128 MiB
  const size_t OFF_RK = OFF_SU + SZ_SU;
  const size_t SZ_RK = (size_t)KP * TSTEPS * 2;                  // 64 MiB
  const size_t FULL = OFF_RK + SZ_RK;                            // 320 MiB

  if (ws_size >= FULL) {
    // Tier A: merge-path resampling.
    char* ws = (char*)d_ws;
    float* zT = (float*)ws;
    float* su = (float*)(ws + OFF_SU);
    unsigned short* rk = (unsigned short*)(ws + OFF_RK);
    transpose_k<<<dim3(TSTEPS / 32, KP / 32), dim3(32, 8), 0, stream>>>(z, zT);
    sortu_k<<<TSTEPS, BLOCK, 0, stream>>>(u, su, rk);
    const size_t shmem3 =
        (size_t)(KP + (KP + 8) + (KP + 8) + KP + NWAVES) * sizeof(float);
    smc_scan3<<<1, BLOCK, shmem3, stream>>>(x, w0, zT, su, rk, out);
  } else {
    // Tier B/C: proven round-6 kernel.
    const size_t shmem =
        (size_t)(3 * KP + BLOCK + NWAVES + NWAVES + 4 + NBUCK + 1) * sizeof(float);
    if (ws_size >= SZ_ZT) {
      float* zT = (float*)d_ws;
      transpose_k<<<dim3(TSTEPS / 32, KP / 32), dim3(32, 8), 0, stream>>>(z, zT);
      smc_scan<true><<<1, BLOCK, shmem, stream>>>(x, w0, zT, u, out);
    } else {
      smc_scan<false><<<1, BLOCK, shmem, stream>>>(x, w0, z, u, out);
    }
  }
}